// Round 8
// baseline (105.337 us; speedup 1.0000x reference)
//
#include <hip/hip_runtime.h>

// SoftErosion3D, connectivity=6, iterations=2, [2,1,256,256,256] f32.
//   iter1(x) = x^2 * prod(6 face nbrs), pad 1.0 ; out = iter1(iter1(im))
// Fused, no LDS, no barriers. Wave = full W row (64 lanes x float4); w+-1 via
// intra-wave shuffles. R7: each thread owns FOUR H rows (h..h+3): interior
// H-neighbor iter1 values are in-register; 2 boundary + 2 outer rows per
// thread. Loads/output f4 = 2.0 (was 3.0). Grid 1024 = exact 4 blocks/CU.

#define DD 256
#define HH 256
#define HW 65536
#define DT 8

typedef float nfloat4 __attribute__((ext_vector_type(4)));

__device__ __forceinline__ float wleft(float x) {     // lane-1's x ; lane0 -> 1.0
    float v = __shfl_up(x, 1, 64);
    return ((threadIdx.x & 63) == 0) ? 1.0f : v;
}
__device__ __forceinline__ float wright(float x) {    // lane+1's x ; lane63 -> 1.0
    float v = __shfl_down(x, 1, 64);
    return ((threadIdx.x & 63) == 63) ? 1.0f : v;
}
__device__ __forceinline__ float4 f4mul(float4 a, float4 b) {
    a.x *= b.x; a.y *= b.y; a.z *= b.z; a.w *= b.w; return a;
}
__device__ __forceinline__ float4 i1core(float4 c) {  // c^2 * W-neighbors
    float lw = wleft(c.w), rw = wright(c.x);
    float4 r;
    r.x = c.x * c.x * (lw  * c.y);
    r.y = c.y * c.y * (c.x * c.z);
    r.z = c.z * c.z * (c.y * c.w);
    r.w = c.w * c.w * (c.z * rw);
    return r;
}
__device__ __forceinline__ int dcl(int d) { return d < 0 ? 0 : (d > DD - 1 ? DD - 1 : d); }

__global__ __launch_bounds__(256, 4) void erode6_fused(const float* __restrict__ in,
                                                       float* __restrict__ out) {
    const int bx  = blockIdx.x;
    const int swz = (bx & 7) * 128 + (bx >> 3);   // 1024 blocks, bijective XCD chunking

    const int cc = threadIdx.x & 63;              // f4 column, w = cc*4
    const int wv = __builtin_amdgcn_readfirstlane((int)(threadIdx.x >> 6));

    const int hblk = swz & 15;          // 16 H-blocks of 16 rows
    const int dchk = (swz >> 4) & 31;   // 32 D-chunks of 8 planes
    const int b    = swz >> 9;          // batch

    const int h = hblk * 16 + wv * 4;   // own rows h..h+3
    const int S = dchk * DT;

    const bool vbU = (h >= 1);
    const bool voU = (h >= 2);
    const bool vbD = (h + 4 <= HH - 1);
    const bool voD = (h + 5 <= HH - 1);
    const int rowU  = vbU ? h - 1 : 0;
    const int rowOU = voU ? h - 2 : 0;
    const int rowD  = vbD ? h + 4 : HH - 1;
    const int rowOD = voD ? h + 5 : HH - 1;

    const float* __restrict__ ip = in  + (size_t)b * (DD * HW);
    float* __restrict__       op = out + (size_t)b * (DD * HW);

    const float* pC0 = ip + ((h + 0) << 8) + (cc << 2);
    const float* pC1 = ip + ((h + 1) << 8) + (cc << 2);
    const float* pC2 = ip + ((h + 2) << 8) + (cc << 2);
    const float* pC3 = ip + ((h + 3) << 8) + (cc << 2);
    const float* pBU = ip + (rowU   << 8) + (cc << 2);
    const float* pBD = ip + (rowD   << 8) + (cc << 2);
    const float* pOU = ip + (rowOU  << 8) + (cc << 2);
    const float* pOD = ip + (rowOD  << 8) + (cc << 2);
    float* pO = op + (h << 8) + (cc << 2);

#define LD(p, pl) (*reinterpret_cast<const float4*>((p) + ((pl) << 16)))

    const int Sm1 = S >= 1 ? S - 1 : 0;
    const int Sm2 = S >= 2 ? S - 2 : 0;

    // ---- prologue raw planes (rolling state) ----
    float4 c0a = LD(pC0, S), c0b = LD(pC0, S + 1), c0c = LD(pC0, S + 2);
    float4 c1a = LD(pC1, S), c1b = LD(pC1, S + 1), c1c = LD(pC1, S + 2);
    float4 c2a = LD(pC2, S), c2b = LD(pC2, S + 1), c2c = LD(pC2, S + 2);
    float4 c3a = LD(pC3, S), c3b = LD(pC3, S + 1), c3c = LD(pC3, S + 2);
    float4 bu_m = LD(pBU, Sm1), bu_c = LD(pBU, S), bu_p = LD(pBU, S + 1);
    float4 bd_m = LD(pBD, Sm1), bd_c = LD(pBD, S), bd_p = LD(pBD, S + 1);

    float4 i0m, i1m, i2m, i3m, i0c, i1c, i2c, i3c;
    {
        float4 c0m1 = LD(pC0, Sm1), c1m1 = LD(pC1, Sm1);
        float4 c2m1 = LD(pC2, Sm1), c3m1 = LD(pC3, Sm1);
        float4 c0m2 = LD(pC0, Sm2), c1m2 = LD(pC1, Sm2);
        float4 c2m2 = LD(pC2, Sm2), c3m2 = LD(pC3, Sm2);

        // i*_m = iter1(S-1, row) — garbage at S==0, never used (guarded by fm)
        i0m = i1core(c0m1); i0m = f4mul(i0m, c0a);
        if (S >= 2) i0m = f4mul(i0m, c0m2);
        if (vbU)    i0m = f4mul(i0m, bu_m);
        i0m = f4mul(i0m, c1m1);

        i1m = i1core(c1m1); i1m = f4mul(i1m, c1a);
        if (S >= 2) i1m = f4mul(i1m, c1m2);
        i1m = f4mul(i1m, c0m1); i1m = f4mul(i1m, c2m1);

        i2m = i1core(c2m1); i2m = f4mul(i2m, c2a);
        if (S >= 2) i2m = f4mul(i2m, c2m2);
        i2m = f4mul(i2m, c1m1); i2m = f4mul(i2m, c3m1);

        i3m = i1core(c3m1); i3m = f4mul(i3m, c3a);
        if (S >= 2) i3m = f4mul(i3m, c3m2);
        i3m = f4mul(i3m, c2m1);
        if (vbD)    i3m = f4mul(i3m, bd_m);

        // i*_c = iter1(S, row)
        i0c = i1core(c0a);
        if (S >= 1) i0c = f4mul(i0c, c0m1);
        i0c = f4mul(i0c, c0b);
        if (vbU)    i0c = f4mul(i0c, bu_c);
        i0c = f4mul(i0c, c1a);

        i1c = i1core(c1a);
        if (S >= 1) i1c = f4mul(i1c, c1m1);
        i1c = f4mul(i1c, c1b);
        i1c = f4mul(i1c, c0a); i1c = f4mul(i1c, c2a);

        i2c = i1core(c2a);
        if (S >= 1) i2c = f4mul(i2c, c2m1);
        i2c = f4mul(i2c, c2b);
        i2c = f4mul(i2c, c1a); i2c = f4mul(i2c, c3a);

        i3c = i1core(c3a);
        if (S >= 1) i3c = f4mul(i3c, c3m1);
        i3c = f4mul(i3c, c3b);
        i3c = f4mul(i3c, c2a);
        if (vbD)    i3c = f4mul(i3c, bd_c);
    }

    for (int t = S; t < S + DT; ++t) {
        const bool fm  = (t > 0);
        const bool fp  = (t < DD - 1);
        const bool fD2 = (t < DD - 2);

        // ---- boundary-row iter1 at plane t (outer rows loaded at use) ----
        float4 IbU = {1.f, 1.f, 1.f, 1.f};
        if (vbU) {
            float4 ouv = LD(pOU, t);
            IbU = i1core(bu_c);
            if (fm)  IbU = f4mul(IbU, bu_m);
            if (fp)  IbU = f4mul(IbU, bu_p);
            if (voU) IbU = f4mul(IbU, ouv);
            IbU = f4mul(IbU, c0a);
        }
        float4 IbD = {1.f, 1.f, 1.f, 1.f};
        if (vbD) {
            float4 odv = LD(pOD, t);
            IbD = i1core(bd_c);
            if (fm)  IbD = f4mul(IbD, bd_m);
            if (fp)  IbD = f4mul(IbD, bd_p);
            IbD = f4mul(IbD, c3a);
            if (voD) IbD = f4mul(IbD, odv);
        }

        // ---- iter1(t+1, own rows) ----
        float4 i0p = i1core(c0b);
        i0p = f4mul(i0p, c0a);
        if (fD2) i0p = f4mul(i0p, c0c);
        if (vbU) i0p = f4mul(i0p, bu_p);
        i0p = f4mul(i0p, c1b);

        float4 i1p = i1core(c1b);
        i1p = f4mul(i1p, c1a);
        if (fD2) i1p = f4mul(i1p, c1c);
        i1p = f4mul(i1p, c0b); i1p = f4mul(i1p, c2b);

        float4 i2p = i1core(c2b);
        i2p = f4mul(i2p, c2a);
        if (fD2) i2p = f4mul(i2p, c2c);
        i2p = f4mul(i2p, c1b); i2p = f4mul(i2p, c3b);

        float4 i3p = i1core(c3b);
        i3p = f4mul(i3p, c3a);
        if (fD2) i3p = f4mul(i3p, c3c);
        i3p = f4mul(i3p, c2b);
        if (vbD) i3p = f4mul(i3p, bd_p);

        // ---- roll raw planes; loads land directly in rolled slots ----
        c0a = c0b; c0b = c0c; c0c = LD(pC0, dcl(t + 3));
        c1a = c1b; c1b = c1c; c1c = LD(pC1, dcl(t + 3));
        c2a = c2b; c2b = c2c; c2c = LD(pC2, dcl(t + 3));
        c3a = c3b; c3b = c3c; c3c = LD(pC3, dcl(t + 3));
        bu_m = bu_c; bu_c = bu_p; bu_p = LD(pBU, dcl(t + 2));
        bd_m = bd_c; bd_c = bd_p; bd_p = LD(pBD, dcl(t + 2));

        // ---- iter2 outputs at plane t ----
        float4 o = i1core(i0c);
        if (fm) o = f4mul(o, i0m);
        if (fp) o = f4mul(o, i0p);
        o = f4mul(o, IbU); o = f4mul(o, i1c);
        nfloat4 v0 = {o.x, o.y, o.z, o.w};
        __builtin_nontemporal_store(v0, reinterpret_cast<nfloat4*>(pO + (t << 16)));

        o = i1core(i1c);
        if (fm) o = f4mul(o, i1m);
        if (fp) o = f4mul(o, i1p);
        o = f4mul(o, i0c); o = f4mul(o, i2c);
        nfloat4 v1 = {o.x, o.y, o.z, o.w};
        __builtin_nontemporal_store(v1, reinterpret_cast<nfloat4*>(pO + (t << 16) + 256));

        o = i1core(i2c);
        if (fm) o = f4mul(o, i2m);
        if (fp) o = f4mul(o, i2p);
        o = f4mul(o, i1c); o = f4mul(o, i3c);
        nfloat4 v2 = {o.x, o.y, o.z, o.w};
        __builtin_nontemporal_store(v2, reinterpret_cast<nfloat4*>(pO + (t << 16) + 512));

        o = i1core(i3c);
        if (fm) o = f4mul(o, i3m);
        if (fp) o = f4mul(o, i3p);
        o = f4mul(o, i2c); o = f4mul(o, IbD);
        nfloat4 v3 = {o.x, o.y, o.z, o.w};
        __builtin_nontemporal_store(v3, reinterpret_cast<nfloat4*>(pO + (t << 16) + 768));

        // ---- roll iter1 pipeline ----
        i0m = i0c; i0c = i0p;
        i1m = i1c; i1c = i1p;
        i2m = i2c; i2c = i2p;
        i3m = i3c; i3c = i3p;
    }
#undef LD
}

extern "C" void kernel_launch(void* const* d_in, const int* in_sizes, int n_in,
                              void* d_out, int out_size, void* d_ws, size_t ws_size,
                              hipStream_t stream) {
    const float* in  = (const float*)d_in[0];
    float*       out = (float*)d_out;

    // 16 H-blocks (16 rows) * 32 D-chunks (8 planes) * 2 batch = 1024 blocks
    dim3 block(256);
    dim3 grid(1024);
    erode6_fused<<<grid, block, 0, stream>>>(in, out);
}

// Round 9
// 47.416 us; speedup vs baseline: 2.2216x; 2.2216x over previous
//
#include <hip/hip_runtime.h>

// SoftErosion3D, connectivity=6, iterations=2, [2,1,256,256,256] f32.
//   iter1(x) = x^2 * prod(6 face nbrs), pad 1.0 ; out = iter1(iter1(im))
// Fused, no LDS, no barriers. Wave = full W row (64 lanes x float4); w+-1 via
// intra-wave shuffles. Thread owns rows h,h+1 (R5/R6 proven structure).
// R8: DT=16 (amortize chunk prologue), 1-deep prefetch, no min-wave bound.

#define DD 256
#define HH 256
#define HW 65536
#define DT 16

typedef float nfloat4 __attribute__((ext_vector_type(4)));

__device__ __forceinline__ float wleft(float x) {     // lane-1's x ; lane0 -> 1.0
    float v = __shfl_up(x, 1, 64);
    return ((threadIdx.x & 63) == 0) ? 1.0f : v;
}
__device__ __forceinline__ float wright(float x) {    // lane+1's x ; lane63 -> 1.0
    float v = __shfl_down(x, 1, 64);
    return ((threadIdx.x & 63) == 63) ? 1.0f : v;
}
__device__ __forceinline__ float4 f4mul(float4 a, float4 b) {
    a.x *= b.x; a.y *= b.y; a.z *= b.z; a.w *= b.w; return a;
}
__device__ __forceinline__ float4 i1core(float4 c) {  // c^2 * W-neighbors
    float lw = wleft(c.w), rw = wright(c.x);
    float4 r;
    r.x = c.x * c.x * (lw  * c.y);
    r.y = c.y * c.y * (c.x * c.z);
    r.z = c.z * c.z * (c.y * c.w);
    r.w = c.w * c.w * (c.z * rw);
    return r;
}
__device__ __forceinline__ int dcl(int d) { return d < 0 ? 0 : (d > DD - 1 ? DD - 1 : d); }

__global__ __launch_bounds__(256) void erode6_fused(const float* __restrict__ in,
                                                    float* __restrict__ out) {
    const int bx  = blockIdx.x;
    const int swz = (bx & 7) * 128 + (bx >> 3);   // 1024 blocks, bijective XCD chunking

    const int cc = threadIdx.x & 63;              // f4 column, w = cc*4
    const int wv = __builtin_amdgcn_readfirstlane((int)(threadIdx.x >> 6));

    const int hblk = swz & 31;          // 32 H-blocks of 8 rows
    const int dchk = (swz >> 5) & 15;   // 16 D-chunks of 16 planes
    const int b    = swz >> 9;          // batch

    const int h = hblk * 8 + wv * 2;    // own rows h, h+1
    const int S = dchk * DT;

    const bool vbU = (h >= 1);
    const bool voU = (h >= 2);
    const bool vbD = (h + 2 <= HH - 1);
    const bool voD = (h + 3 <= HH - 1);
    const int rowU  = vbU ? h - 1 : 0;
    const int rowOU = voU ? h - 2 : 0;
    const int rowD  = vbD ? h + 2 : HH - 1;
    const int rowOD = voD ? h + 3 : HH - 1;

    const float* __restrict__ ip = in  + (size_t)b * (DD * HW);
    float* __restrict__       op = out + (size_t)b * (DD * HW);

    const float* pC0 = ip + (h     << 8) + (cc << 2);
    const float* pC1 = ip + ((h+1) << 8) + (cc << 2);
    const float* pBU = ip + (rowU  << 8) + (cc << 2);
    const float* pBD = ip + (rowD  << 8) + (cc << 2);
    const float* pOU = ip + (rowOU << 8) + (cc << 2);
    const float* pOD = ip + (rowOD << 8) + (cc << 2);
    float* pO0 = op + (h << 8) + (cc << 2);

#define LD(p, pl) (*reinterpret_cast<const float4*>((p) + ((pl) << 16)))

    const int Sm1 = S >= 1 ? S - 1 : 0;
    const int Sm2 = S >= 2 ? S - 2 : 0;

    // ---- prologue loads ----
    float4 c0_m2 = LD(pC0, Sm2), c0_m1 = LD(pC0, Sm1);
    float4 c0_t  = LD(pC0, S), c0_t1 = LD(pC0, S + 1), c0_t2 = LD(pC0, S + 2);
    float4 c1_m2 = LD(pC1, Sm2), c1_m1 = LD(pC1, Sm1);
    float4 c1_t  = LD(pC1, S), c1_t1 = LD(pC1, S + 1), c1_t2 = LD(pC1, S + 2);
    float4 bu_m = LD(pBU, Sm1), bu_c = LD(pBU, S), bu_p = LD(pBU, S + 1);
    float4 bd_m = LD(pBD, Sm1), bd_c = LD(pBD, S), bd_p = LD(pBD, S + 1);
    float4 ou = LD(pOU, S), od = LD(pOD, S);

    // i*_m = iter1(S-1, row) — garbage at S==0, never used (guarded by fm)
    float4 i0_m = i1core(c0_m1);
    i0_m = f4mul(i0_m, c0_t);
    if (S >= 2) i0_m = f4mul(i0_m, c0_m2);
    if (vbU)    i0_m = f4mul(i0_m, bu_m);
    i0_m = f4mul(i0_m, c1_m1);

    float4 i1_m = i1core(c1_m1);
    i1_m = f4mul(i1_m, c1_t);
    if (S >= 2) i1_m = f4mul(i1_m, c1_m2);
    i1_m = f4mul(i1_m, c0_m1);
    if (vbD)    i1_m = f4mul(i1_m, bd_m);

    // i*_c = iter1(S, row)
    float4 i0_c = i1core(c0_t);
    if (S >= 1) i0_c = f4mul(i0_c, c0_m1);
    i0_c = f4mul(i0_c, c0_t1);
    if (vbU)    i0_c = f4mul(i0_c, bu_c);
    i0_c = f4mul(i0_c, c1_t);

    float4 i1_c = i1core(c1_t);
    if (S >= 1) i1_c = f4mul(i1_c, c1_m1);
    i1_c = f4mul(i1_c, c1_t1);
    i1_c = f4mul(i1_c, c0_t);
    if (vbD)    i1_c = f4mul(i1_c, bd_c);

#pragma unroll
    for (int k = 0; k < DT; ++k) {
        const int t = S + k;

        // ---- 1-deep prefetch for next step ----
        float4 pf_c0 = LD(pC0, dcl(t + 3)), pf_c1 = LD(pC1, dcl(t + 3));
        float4 pf_bu = LD(pBU, dcl(t + 2)), pf_bd = LD(pBD, dcl(t + 2));
        float4 pf_ou = LD(pOU, dcl(t + 1)), pf_od = LD(pOD, dcl(t + 1));

        const bool fm  = (t > 0);
        const bool fp  = (t < DD - 1);
        const bool fD2 = (t < DD - 2);

        // ---- boundary-row iter1 at plane t ----
        float4 IbU = {1.f, 1.f, 1.f, 1.f};
        if (vbU) {
            IbU = i1core(bu_c);
            if (fm)  IbU = f4mul(IbU, bu_m);
            if (fp)  IbU = f4mul(IbU, bu_p);
            if (voU) IbU = f4mul(IbU, ou);
            IbU = f4mul(IbU, c0_t);
        }
        float4 IbD = {1.f, 1.f, 1.f, 1.f};
        if (vbD) {
            IbD = i1core(bd_c);
            if (fm)  IbD = f4mul(IbD, bd_m);
            if (fp)  IbD = f4mul(IbD, bd_p);
            IbD = f4mul(IbD, c1_t);
            if (voD) IbD = f4mul(IbD, od);
        }

        // ---- iter1(t+1, own rows) ----
        float4 i0_p = i1core(c0_t1);
        i0_p = f4mul(i0_p, c0_t);
        if (fD2) i0_p = f4mul(i0_p, c0_t2);
        if (vbU) i0_p = f4mul(i0_p, bu_p);
        i0_p = f4mul(i0_p, c1_t1);

        float4 i1_p = i1core(c1_t1);
        i1_p = f4mul(i1_p, c1_t);
        if (fD2) i1_p = f4mul(i1_p, c1_t2);
        i1_p = f4mul(i1_p, c0_t1);
        if (vbD) i1_p = f4mul(i1_p, bd_p);

        // ---- iter2 outputs at plane t ----
        float4 o0 = i1core(i0_c);
        if (fm) o0 = f4mul(o0, i0_m);
        if (fp) o0 = f4mul(o0, i0_p);
        o0 = f4mul(o0, IbU);
        o0 = f4mul(o0, i1_c);       // row h+1's iter1 — in-register H-neighbor

        float4 o1 = i1core(i1_c);
        if (fm) o1 = f4mul(o1, i1_m);
        if (fp) o1 = f4mul(o1, i1_p);
        o1 = f4mul(o1, i0_c);
        o1 = f4mul(o1, IbD);

        nfloat4 v0 = {o0.x, o0.y, o0.z, o0.w};
        nfloat4 v1 = {o1.x, o1.y, o1.z, o1.w};
        __builtin_nontemporal_store(v0, reinterpret_cast<nfloat4*>(pO0 + (t << 16)));
        __builtin_nontemporal_store(v1, reinterpret_cast<nfloat4*>(pO0 + (t << 16) + 256));

        // ---- roll (register renaming under full unroll) ----
        i0_m = i0_c; i0_c = i0_p; i1_m = i1_c; i1_c = i1_p;
        c0_t = c0_t1; c0_t1 = c0_t2; c0_t2 = pf_c0;
        c1_t = c1_t1; c1_t1 = c1_t2; c1_t2 = pf_c1;
        bu_m = bu_c; bu_c = bu_p; bu_p = pf_bu;
        bd_m = bd_c; bd_c = bd_p; bd_p = pf_bd;
        ou = pf_ou; od = pf_od;
    }
#undef LD
}

extern "C" void kernel_launch(void* const* d_in, const int* in_sizes, int n_in,
                              void* d_out, int out_size, void* d_ws, size_t ws_size,
                              hipStream_t stream) {
    const float* in  = (const float*)d_in[0];
    float*       out = (float*)d_out;

    // 32 H-blocks (8 rows) * 16 D-chunks (16 planes) * 2 batch = 1024 blocks
    dim3 block(256);
    dim3 grid(1024);
    erode6_fused<<<grid, block, 0, stream>>>(in, out);
}